// Round 3
// baseline (17514.078 us; speedup 1.0000x reference)
//
#include <hip/hip_runtime.h>
#include <hip/hip_bf16.h>

typedef __attribute__((ext_vector_type(4))) _Float16 half4;
typedef __attribute__((ext_vector_type(8))) _Float16 half8;
typedef __attribute__((ext_vector_type(4))) float f32x4;

#define T_ 512
#define B_ 256
#define I_ 64
#define H_ 512
#define G_ 2048
#define BH (B_ * H_)

#define NKS0 36   // (64 + 512) / 16
#define NKS1 64   // (512 + 512) / 16

// ---------------- weight packing ----------------
// Element offset: (((nb*4 + w)*NKS + ks)*64 + l)*8 + j*4 + i
//   col = nb*32 + j*16 + (l&15);  g = w*512 + col;  k = ks*16 + (l>>4)*4 + i
template<int NKS, int K0>
__global__ void pack_w(const float* __restrict__ Wih, const float* __restrict__ Whh,
                       _Float16* __restrict__ Wp) {
    int idx = blockIdx.x * 256 + threadIdx.x;
    int i = idx & 3;
    int j = (idx >> 2) & 1;
    int l = (idx >> 3) & 63;
    int rest = idx >> 9;
    int ks = rest % NKS;
    int r  = rest / NKS;
    int w  = r & 3;
    int nb = r >> 2;
    int col = nb * 32 + j * 16 + (l & 15);
    int g   = w * H_ + col;
    int k   = ks * 16 + ((l >> 4) << 2) + i;
    float v = (k < K0) ? Wih[(size_t)g * K0 + k] : Whh[(size_t)g * H_ + (k - K0)];
    Wp[idx] = (_Float16)v;
}

// ---------------- group barrier (32 blocks of one batch-group) ----------------
__device__ __forceinline__ void group_barrier(unsigned* cnt, unsigned* gen, unsigned it) {
    __syncthreads();
    if (threadIdx.x == 0) {
        __threadfence();   // release: make h stores visible device-wide
        unsigned prev = __hip_atomic_fetch_add(cnt, 1u, __ATOMIC_ACQ_REL, __HIP_MEMORY_SCOPE_AGENT);
        if (prev == it * 32u + 31u) {
            __hip_atomic_store(gen, it + 1u, __ATOMIC_RELEASE, __HIP_MEMORY_SCOPE_AGENT);
        } else {
            while (__hip_atomic_load(gen, __ATOMIC_ACQUIRE, __HIP_MEMORY_SCOPE_AGENT) < it + 1u) {
                __builtin_amdgcn_s_sleep(4);
            }
        }
    }
    __syncthreads();
}

// ---------------- LSTM cell epilogue ----------------
__device__ __forceinline__ void cell_epilogue(
    f32x4 (&acc)[2][2], float (*gbuf)[32][36], int w, int lk, int lr,
    const float (&bias)[4][4], f32x4& cst, int crow, int ccol,
    _Float16* __restrict__ dst, int R0, int nb)
{
    #pragma unroll
    for (int m = 0; m < 2; ++m)
        #pragma unroll
        for (int j = 0; j < 2; ++j)
            #pragma unroll
            for (int r = 0; r < 4; ++r)
                gbuf[w][m * 16 + lk * 4 + r][j * 16 + lr] = acc[m][j][r];
    __syncthreads();

    f32x4 gv[4];
    #pragma unroll
    for (int q = 0; q < 4; ++q)
        gv[q] = *(const f32x4*)&gbuf[q][crow][ccol];

    half4 hv;
    #pragma unroll
    for (int cc = 0; cc < 4; ++cc) {
        float gi = gv[0][cc] + bias[0][cc];
        float gf = gv[1][cc] + bias[1][cc];
        float gg = gv[2][cc] + bias[2][cc];
        float go = gv[3][cc] + bias[3][cc];
        float si = 1.f / (1.f + __expf(-gi));
        float sf = 1.f / (1.f + __expf(-gf));
        float tg = tanhf(gg);
        float so = 1.f / (1.f + __expf(-go));
        float cn = sf * cst[cc] + si * tg;
        cst[cc] = cn;
        float th = tanhf(cn);
        hv[cc] = (_Float16)(so * th);
    }
    *(half4*)&dst[(size_t)(R0 + crow) * H_ + nb * 32 + ccol] = hv;
}

// ---------------- persistent LSTM ----------------
// 256 blocks, plain launch (1 block/CU by resource math -> all resident).
// group g = bid&7 (32 batch rows); lid = bid>>3: lid<16 -> layer0, else layer1.
// Block owns 32 batch rows x 32 hidden cols (all 4 gates). Wave w = gate w.
// Weights resident in VGPRs; c-state in VGPRs; h via global (L2/LLC).
__global__ __launch_bounds__(256, 1) void lstm_persistent(
    const float* __restrict__ x,
    const _Float16* __restrict__ Wp0,
    const _Float16* __restrict__ Wp1,
    const float* __restrict__ bih0, const float* __restrict__ bhh0,
    const float* __restrict__ bih1, const float* __restrict__ bhh1,
    _Float16* __restrict__ h1buf,
    _Float16* __restrict__ h2buf,
    unsigned* __restrict__ bar)
{
    const int bid = blockIdx.x;
    const int g   = bid & 7;
    const int lid = bid >> 3;
    const int layer = lid >> 4;
    const int nb  = lid & 15;
    const int tid = threadIdx.x;
    const int w   = tid >> 6;
    const int l   = tid & 63;
    const int lr  = l & 15;
    const int lk  = l >> 4;
    const int R0  = g * 32;

    __shared__ float gbuf[4][32][36];

    unsigned* cnt = bar + (size_t)g * 128;
    unsigned* gen = cnt + 64;

    const int crow = tid >> 3;
    const int ccol = (tid & 7) << 2;

    float bias[4][4];
    {
        const float* bi = layer ? bih1 : bih0;
        const float* bh = layer ? bhh1 : bhh0;
        #pragma unroll
        for (int q = 0; q < 4; ++q)
            #pragma unroll
            for (int cc = 0; cc < 4; ++cc) {
                int gc = q * H_ + nb * 32 + ccol + cc;
                bias[q][cc] = bi[gc] + bh[gc];
            }
    }

    f32x4 cst = {0.f, 0.f, 0.f, 0.f};

    if (layer == 0) {
        half4 breg[2 * NKS0];
        const _Float16* wbase = Wp0 + (size_t)(nb * 4 + w) * NKS0 * 512 + l * 8;
        #pragma unroll
        for (int ks = 0; ks < NKS0; ++ks) {
            half8 t = *(const half8*)(wbase + ks * 512);
            breg[2 * ks]     = __builtin_shufflevector(t, t, 0, 1, 2, 3);
            breg[2 * ks + 1] = __builtin_shufflevector(t, t, 4, 5, 6, 7);
        }
        const float* ax0 = x + (size_t)(R0 + lr) * (T_ * I_) + lk * 4;
        const float* ax1 = x + (size_t)(R0 + 16 + lr) * (T_ * I_) + lk * 4;

        for (int tt = 0; tt <= T_; ++tt) {
            if (tt < T_) {
                const int t = tt;
                const _Float16* hp  = h1buf + ((t - 1) & 1) * BH;
                const _Float16* ah0 = hp + (size_t)(R0 + lr) * H_ + lk * 4;
                const _Float16* ah1 = hp + (size_t)(R0 + 16 + lr) * H_ + lk * 4;
                const float* xx0 = ax0 + t * I_;
                const float* xx1 = ax1 + t * I_;

                f32x4 acc[2][2];
                #pragma unroll
                for (int m = 0; m < 2; ++m)
                    #pragma unroll
                    for (int j = 0; j < 2; ++j)
                        acc[m][j] = f32x4{0.f, 0.f, 0.f, 0.f};

                #pragma unroll
                for (int ks = 0; ks < NKS0; ++ks) {
                    half4 a0, a1;
                    if (ks < 4) {
                        f32x4 v0 = *(const f32x4*)(xx0 + ks * 16);
                        f32x4 v1 = *(const f32x4*)(xx1 + ks * 16);
                        a0 = half4{(_Float16)v0[0], (_Float16)v0[1], (_Float16)v0[2], (_Float16)v0[3]};
                        a1 = half4{(_Float16)v1[0], (_Float16)v1[1], (_Float16)v1[2], (_Float16)v1[3]};
                    } else {
                        a0 = *(const half4*)(ah0 + (ks - 4) * 16);
                        a1 = *(const half4*)(ah1 + (ks - 4) * 16);
                    }
                    acc[0][0] = __builtin_amdgcn_mfma_f32_16x16x16f16(a0, breg[2 * ks],     acc[0][0], 0, 0, 0);
                    acc[1][0] = __builtin_amdgcn_mfma_f32_16x16x16f16(a1, breg[2 * ks],     acc[1][0], 0, 0, 0);
                    acc[0][1] = __builtin_amdgcn_mfma_f32_16x16x16f16(a0, breg[2 * ks + 1], acc[0][1], 0, 0, 0);
                    acc[1][1] = __builtin_amdgcn_mfma_f32_16x16x16f16(a1, breg[2 * ks + 1], acc[1][1], 0, 0, 0);
                }
                cell_epilogue(acc, gbuf, w, lk, lr, bias, cst, crow, ccol,
                              h1buf + (t & 1) * BH, R0, nb);
            }
            group_barrier(cnt, gen, (unsigned)tt);
        }
    } else {
        half4 breg[2 * NKS1];
        const _Float16* wbase = Wp1 + (size_t)(nb * 4 + w) * NKS1 * 512 + l * 8;
        #pragma unroll
        for (int ks = 0; ks < NKS1; ++ks) {
            half8 t = *(const half8*)(wbase + ks * 512);
            breg[2 * ks]     = __builtin_shufflevector(t, t, 0, 1, 2, 3);
            breg[2 * ks + 1] = __builtin_shufflevector(t, t, 4, 5, 6, 7);
        }

        for (int tt = 0; tt <= T_; ++tt) {
            if (tt >= 1) {
                const int s = tt - 1;
                const _Float16* h1p = h1buf + (s & 1) * BH;
                const _Float16* h2p = h2buf + ((s - 1) & 1) * BH;
                const _Float16* a00 = h1p + (size_t)(R0 + lr) * H_ + lk * 4;
                const _Float16* a01 = h1p + (size_t)(R0 + 16 + lr) * H_ + lk * 4;
                const _Float16* a10 = h2p + (size_t)(R0 + lr) * H_ + lk * 4;
                const _Float16* a11 = h2p + (size_t)(R0 + 16 + lr) * H_ + lk * 4;

                f32x4 acc[2][2];
                #pragma unroll
                for (int m = 0; m < 2; ++m)
                    #pragma unroll
                    for (int j = 0; j < 2; ++j)
                        acc[m][j] = f32x4{0.f, 0.f, 0.f, 0.f};

                #pragma unroll
                for (int ks = 0; ks < NKS1; ++ks) {
                    half4 a0, a1;
                    if (ks < 32) {
                        a0 = *(const half4*)(a00 + ks * 16);
                        a1 = *(const half4*)(a01 + ks * 16);
                    } else {
                        a0 = *(const half4*)(a10 + (ks - 32) * 16);
                        a1 = *(const half4*)(a11 + (ks - 32) * 16);
                    }
                    acc[0][0] = __builtin_amdgcn_mfma_f32_16x16x16f16(a0, breg[2 * ks],     acc[0][0], 0, 0, 0);
                    acc[1][0] = __builtin_amdgcn_mfma_f32_16x16x16f16(a1, breg[2 * ks],     acc[1][0], 0, 0, 0);
                    acc[0][1] = __builtin_amdgcn_mfma_f32_16x16x16f16(a0, breg[2 * ks + 1], acc[0][1], 0, 0, 0);
                    acc[1][1] = __builtin_amdgcn_mfma_f32_16x16x16f16(a1, breg[2 * ks + 1], acc[1][1], 0, 0, 0);
                }
                cell_epilogue(acc, gbuf, w, lk, lr, bias, cst, crow, ccol,
                              h2buf + (s & 1) * BH, R0, nb);
            }
            group_barrier(cnt, gen, (unsigned)tt);
        }
    }
}

// ---------------- final FC ----------------
__global__ void fc_kernel(const _Float16* __restrict__ h2, const float* __restrict__ Wfc,
                          const float* __restrict__ bfc, float* __restrict__ out) {
    int b = blockIdx.x;
    int lidx = threadIdx.x;
    float s = 0.f;
    #pragma unroll
    for (int h = lidx; h < H_; h += 64) s += (float)h2[b * H_ + h] * Wfc[h];
    #pragma unroll
    for (int off = 32; off; off >>= 1) s += __shfl_down(s, off);
    if (lidx == 0) out[b] = s + bfc[0];
}

extern "C" void kernel_launch(void* const* d_in, const int* in_sizes, int n_in,
                              void* d_out, int out_size, void* d_ws, size_t ws_size,
                              hipStream_t stream) {
    const float* x    = (const float*)d_in[0];
    const float* Wih0 = (const float*)d_in[1];
    const float* Whh0 = (const float*)d_in[2];
    const float* bih0 = (const float*)d_in[3];
    const float* bhh0 = (const float*)d_in[4];
    const float* Wih1 = (const float*)d_in[5];
    const float* Whh1 = (const float*)d_in[6];
    const float* bih1 = (const float*)d_in[7];
    const float* bhh1 = (const float*)d_in[8];
    const float* Wfc  = (const float*)d_in[9];
    const float* bfc  = (const float*)d_in[10];
    float* out = (float*)d_out;

    char* ws = (char*)d_ws;
    unsigned*  bar   = (unsigned*)ws;                               // 4 KB (8 groups x 512 B)
    _Float16*  h1buf = (_Float16*)(ws + 4096);                      // 2 x 256 KB
    _Float16*  h2buf = (_Float16*)(ws + 4096 + 524288);             // 2 x 256 KB
    _Float16*  Wp0   = (_Float16*)(ws + 4096 + 1048576);            // 2359296 B
    _Float16*  Wp1   = (_Float16*)(ws + 4096 + 1048576 + 2359296);  // 4194304 B

    hipMemsetAsync(d_ws, 0, 4096 + 1048576, stream);   // barrier + h buffers = zeros
    pack_w<NKS0, I_><<<4608, 256, 0, stream>>>(Wih0, Whh0, Wp0);
    pack_w<NKS1, H_><<<8192, 256, 0, stream>>>(Wih1, Whh1, Wp1);

    lstm_persistent<<<dim3(256), dim3(256), 0, stream>>>(
        x, Wp0, Wp1, bih0, bhh0, bih1, bhh1, h1buf, h2buf, bar);

    fc_kernel<<<B_, 64, 0, stream>>>(h2buf + BH, Wfc, bfc, out);
}

// Round 4
// 9912.917 us; speedup vs baseline: 1.7668x; 1.7668x over previous
//
#include <hip/hip_runtime.h>
#include <hip/hip_bf16.h>

typedef __attribute__((ext_vector_type(2))) _Float16 half2v;
typedef __attribute__((ext_vector_type(4))) _Float16 half4;
typedef __attribute__((ext_vector_type(8))) _Float16 half8;
typedef __attribute__((ext_vector_type(4))) float f32x4;
typedef __attribute__((ext_vector_type(2))) float f32x2;

#define T_ 512
#define B_ 256
#define I_ 64
#define H_ 512
#define BH (B_ * H_)
#define NKS0 36   // K = 64(x) + 512(h1)
#define NKS1 64   // K = 512(h1) + 512(h2)

#define STRIDE1 1032   // 1024 + 8 halves pad (16B-aligned rows, <=2-way banks)
#define STRIDE0 520    // 512 + 8

// Wp[((cb*4+w)*NKS+ks)*256 + l*4 + i] = W[g = w*512 + cb*16 + (l&15)][k = ks*16 + (l>>4)*4 + i]
template<int NKS, int K0>
__global__ void pack_w(const float* __restrict__ Wih, const float* __restrict__ Whh,
                       _Float16* __restrict__ Wp) {
    int idx = blockIdx.x * 256 + threadIdx.x;
    int i  = idx & 3;
    int l  = (idx >> 2) & 63;
    int rest = idx >> 8;
    int ks = rest % NKS;
    int r  = rest / NKS;
    int w  = r & 3;
    int cb = r >> 2;
    int g  = w * H_ + cb * 16 + (l & 15);
    int k  = ks * 16 + ((l >> 4) << 2) + i;
    float v = (k < K0) ? Wih[(size_t)g * K0 + k] : Whh[(size_t)g * H_ + (k - K0)];
    Wp[idx] = (_Float16)v;
}

// ---- group barrier: 64 blocks; relaxed agent atomics + one release/acquire fence per step ----
__device__ __forceinline__ void group_barrier(unsigned* cnt, unsigned* gen, unsigned it) {
    __syncthreads();                     // also drains this block's h-stores (vmcnt before s_barrier)
    if (threadIdx.x == 0) {
        __builtin_amdgcn_fence(__ATOMIC_RELEASE, "agent");   // write back dirty L2 (h tiles)
        unsigned prev = __hip_atomic_fetch_add(cnt, 1u, __ATOMIC_RELAXED, __HIP_MEMORY_SCOPE_AGENT);
        if (prev == it * 64u + 63u) {
            __hip_atomic_store(gen, it + 1u, __ATOMIC_RELAXED, __HIP_MEMORY_SCOPE_AGENT);
        } else {
            int kpoll = 0;
            while (true) {
                unsigned v = __hip_atomic_load(gen, __ATOMIC_RELAXED, __HIP_MEMORY_SCOPE_AGENT);
                if (v > it) break;
                if ((++kpoll & 15) == 0) {
                    v = __hip_atomic_load(gen, __ATOMIC_ACQUIRE, __HIP_MEMORY_SCOPE_AGENT);
                    if (v > it) break;
                }
                __builtin_amdgcn_s_sleep(2);
            }
        }
        __builtin_amdgcn_fence(__ATOMIC_ACQUIRE, "agent");   // invalidate L1/L2 once per step
    }
    __syncthreads();
}

// ---- persistent LSTM: 512 blocks (2/CU). group g=bid&7 (32 rows); lid=bid>>3:
// lid<32 -> layer0 col-block, else layer1. Block: 32 rows x 16 cols x 4 gates (wave=gate).
__global__ __launch_bounds__(256, 2) void lstm_persistent(
    const float* __restrict__ x,
    const _Float16* __restrict__ Wp0, const _Float16* __restrict__ Wp1,
    const float* __restrict__ bih0, const float* __restrict__ bhh0,
    const float* __restrict__ bih1, const float* __restrict__ bhh1,
    _Float16* __restrict__ h1buf, _Float16* __restrict__ h2buf,
    unsigned* __restrict__ bar)
{
    const int bid = blockIdx.x;
    const int g = bid & 7, lid = bid >> 3;
    const int layer = lid >> 5, cb = lid & 31;
    const int tid = threadIdx.x, w = tid >> 6, l = tid & 63;
    const int lr = l & 15, lk = l >> 4;
    const int R0 = g * 32, c0 = cb * 16;

    __shared__ _Float16 tile[32 * STRIDE1];   // A-tile staging (layer0 uses STRIDE0 region)
    __shared__ float gbuf[4][32][18];

    unsigned* cnt = bar + g * 256;
    unsigned* gen = cnt + 64;

    const int erow = tid >> 3;        // 0..31
    const int ecol = (tid & 7) << 1;  // 0,2,..,14

    float bias_r[4][2];
    {
        const float* bi = layer ? bih1 : bih0;
        const float* bh = layer ? bhh1 : bhh0;
        #pragma unroll
        for (int q = 0; q < 4; ++q)
            #pragma unroll
            for (int cc = 0; cc < 2; ++cc) {
                int gc = q * H_ + c0 + ecol + cc;
                bias_r[q][cc] = bi[gc] + bh[gc];
            }
    }

    f32x2 cst = {0.f, 0.f};

    if (layer == 0) {
        half4 breg[NKS0];
        {
            const _Float16* wb = Wp0 + ((size_t)(cb * 4 + w) * NKS0) * 256 + l * 4;
            #pragma unroll
            for (int ks = 0; ks < NKS0; ++ks) breg[ks] = *(const half4*)(wb + ks * 256);
        }
        const float* ax0 = x + (size_t)(R0 + lr) * (T_ * I_) + lk * 4;
        const float* ax1 = x + (size_t)(R0 + 16 + lr) * (T_ * I_) + lk * 4;

        for (int tt = 0; tt <= T_; ++tt) {
            if (tt < T_) {
                // stage h1[t-1] rows (zeros at t=0 come from memset'd buffer)
                const _Float16* hp = h1buf + ((tt - 1) & 1) * BH;
                #pragma unroll
                for (int it = 0; it < 8; ++it) {
                    int cch = tid + it * 256;
                    int row = cch >> 6, off = (cch & 63) << 3;
                    *(half8*)&tile[row * STRIDE0 + off] =
                        *(const half8*)(hp + (size_t)(R0 + row) * H_ + off);
                }
                __syncthreads();

                f32x4 acc0 = {0.f,0.f,0.f,0.f}, acc1 = {0.f,0.f,0.f,0.f};
                const float* xx0 = ax0 + tt * I_;
                const float* xx1 = ax1 + tt * I_;
                #pragma unroll
                for (int ks = 0; ks < 4; ++ks) {
                    f32x4 v0 = *(const f32x4*)(xx0 + ks * 16);
                    f32x4 v1 = *(const f32x4*)(xx1 + ks * 16);
                    half4 a0 = {(_Float16)v0[0], (_Float16)v0[1], (_Float16)v0[2], (_Float16)v0[3]};
                    half4 a1 = {(_Float16)v1[0], (_Float16)v1[1], (_Float16)v1[2], (_Float16)v1[3]};
                    acc0 = __builtin_amdgcn_mfma_f32_16x16x16f16(a0, breg[ks], acc0, 0, 0, 0);
                    acc1 = __builtin_amdgcn_mfma_f32_16x16x16f16(a1, breg[ks], acc1, 0, 0, 0);
                }
                #pragma unroll
                for (int ks = 4; ks < NKS0; ++ks) {
                    half4 a0 = *(const half4*)&tile[lr * STRIDE0 + (ks - 4) * 16 + lk * 4];
                    half4 a1 = *(const half4*)&tile[(lr + 16) * STRIDE0 + (ks - 4) * 16 + lk * 4];
                    acc0 = __builtin_amdgcn_mfma_f32_16x16x16f16(a0, breg[ks], acc0, 0, 0, 0);
                    acc1 = __builtin_amdgcn_mfma_f32_16x16x16f16(a1, breg[ks], acc1, 0, 0, 0);
                }

                // epilogue
                #pragma unroll
                for (int r = 0; r < 4; ++r) {
                    gbuf[w][lk * 4 + r][lr]      = acc0[r];
                    gbuf[w][16 + lk * 4 + r][lr] = acc1[r];
                }
                __syncthreads();
                f32x2 gv[4];
                #pragma unroll
                for (int q = 0; q < 4; ++q) gv[q] = *(const f32x2*)&gbuf[q][erow][ecol];
                half2v hv;
                #pragma unroll
                for (int cc = 0; cc < 2; ++cc) {
                    float gi = gv[0][cc] + bias_r[0][cc];
                    float gf = gv[1][cc] + bias_r[1][cc];
                    float gg = gv[2][cc] + bias_r[2][cc];
                    float go = gv[3][cc] + bias_r[3][cc];
                    float si = 1.f / (1.f + __expf(-gi));
                    float sf = 1.f / (1.f + __expf(-gf));
                    float tg = tanhf(gg);
                    float so = 1.f / (1.f + __expf(-go));
                    float cn = sf * cst[cc] + si * tg;
                    cst[cc] = cn;
                    hv[cc] = (_Float16)(so * tanhf(cn));
                }
                _Float16* dst = h1buf + (tt & 1) * BH;
                *(half2v*)&dst[(size_t)(R0 + erow) * H_ + c0 + ecol] = hv;
            }
            if (tt < T_) group_barrier(cnt, gen, (unsigned)tt);
        }
    } else {
        half4 breg[NKS1];
        {
            const _Float16* wb = Wp1 + ((size_t)(cb * 4 + w) * NKS1) * 256 + l * 4;
            #pragma unroll
            for (int ks = 0; ks < NKS1; ++ks) breg[ks] = *(const half4*)(wb + ks * 256);
        }

        for (int tt = 0; tt <= T_; ++tt) {
            if (tt >= 1) {
                const int s = tt - 1;
                const _Float16* h1p = h1buf + (s & 1) * BH;
                const _Float16* h2p = h2buf + ((s - 1) & 1) * BH;
                #pragma unroll
                for (int it = 0; it < 16; ++it) {
                    int cch = tid + it * 256;
                    int row = cch >> 7, off = (cch & 127) << 3;
                    const _Float16* src = (off < 512)
                        ? h1p + (size_t)(R0 + row) * H_ + off
                        : h2p + (size_t)(R0 + row) * H_ + (off - 512);
                    *(half8*)&tile[row * STRIDE1 + off] = *(const half8*)src;
                }
                __syncthreads();

                f32x4 acc0 = {0.f,0.f,0.f,0.f}, acc1 = {0.f,0.f,0.f,0.f};
                #pragma unroll
                for (int ks = 0; ks < NKS1; ++ks) {
                    half4 a0 = *(const half4*)&tile[lr * STRIDE1 + ks * 16 + lk * 4];
                    half4 a1 = *(const half4*)&tile[(lr + 16) * STRIDE1 + ks * 16 + lk * 4];
                    acc0 = __builtin_amdgcn_mfma_f32_16x16x16f16(a0, breg[ks], acc0, 0, 0, 0);
                    acc1 = __builtin_amdgcn_mfma_f32_16x16x16f16(a1, breg[ks], acc1, 0, 0, 0);
                }

                #pragma unroll
                for (int r = 0; r < 4; ++r) {
                    gbuf[w][lk * 4 + r][lr]      = acc0[r];
                    gbuf[w][16 + lk * 4 + r][lr] = acc1[r];
                }
                __syncthreads();
                f32x2 gv[4];
                #pragma unroll
                for (int q = 0; q < 4; ++q) gv[q] = *(const f32x2*)&gbuf[q][erow][ecol];
                half2v hv;
                #pragma unroll
                for (int cc = 0; cc < 2; ++cc) {
                    float gi = gv[0][cc] + bias_r[0][cc];
                    float gf = gv[1][cc] + bias_r[1][cc];
                    float gg = gv[2][cc] + bias_r[2][cc];
                    float go = gv[3][cc] + bias_r[3][cc];
                    float si = 1.f / (1.f + __expf(-gi));
                    float sf = 1.f / (1.f + __expf(-gf));
                    float tg = tanhf(gg);
                    float so = 1.f / (1.f + __expf(-go));
                    float cn = sf * cst[cc] + si * tg;
                    cst[cc] = cn;
                    hv[cc] = (_Float16)(so * tanhf(cn));
                }
                _Float16* dst = h2buf + (s & 1) * BH;
                *(half2v*)&dst[(size_t)(R0 + erow) * H_ + c0 + ecol] = hv;
            }
            if (tt < T_) group_barrier(cnt, gen, (unsigned)tt);
        }
    }
}

__global__ void fc_kernel(const _Float16* __restrict__ h2, const float* __restrict__ Wfc,
                          const float* __restrict__ bfc, float* __restrict__ out) {
    int b = blockIdx.x;
    int lidx = threadIdx.x;
    float s = 0.f;
    #pragma unroll
    for (int h = lidx; h < H_; h += 64) s += (float)h2[b * H_ + h] * Wfc[h];
    #pragma unroll
    for (int off = 32; off; off >>= 1) s += __shfl_down(s, off);
    if (lidx == 0) out[b] = s + bfc[0];
}

extern "C" void kernel_launch(void* const* d_in, const int* in_sizes, int n_in,
                              void* d_out, int out_size, void* d_ws, size_t ws_size,
                              hipStream_t stream) {
    const float* x    = (const float*)d_in[0];
    const float* Wih0 = (const float*)d_in[1];
    const float* Whh0 = (const float*)d_in[2];
    const float* bih0 = (const float*)d_in[3];
    const float* bhh0 = (const float*)d_in[4];
    const float* Wih1 = (const float*)d_in[5];
    const float* Whh1 = (const float*)d_in[6];
    const float* bih1 = (const float*)d_in[7];
    const float* bhh1 = (const float*)d_in[8];
    const float* Wfc  = (const float*)d_in[9];
    const float* bfc  = (const float*)d_in[10];
    float* out = (float*)d_out;

    char* ws = (char*)d_ws;
    unsigned*  bar   = (unsigned*)ws;                       // 8 KB (8 groups x 1 KB)
    _Float16*  h1buf = (_Float16*)(ws + 8192);              // 2 x 256 KB
    _Float16*  h2buf = (_Float16*)(ws + 8192 + 524288);     // 2 x 256 KB
    _Float16*  Wp0   = (_Float16*)(ws + 8192 + 1048576);    // 2359296 B
    _Float16*  Wp1   = (_Float16*)(ws + 8192 + 1048576 + 2359296);  // 4194304 B

    hipMemsetAsync(d_ws, 0, 8192 + 1048576, stream);   // barriers + h parity buffers
    pack_w<NKS0, I_><<<4608, 256, 0, stream>>>(Wih0, Whh0, Wp0);
    pack_w<NKS1, H_><<<8192, 256, 0, stream>>>(Wih1, Whh1, Wp1);

    lstm_persistent<<<dim3(512), dim3(256), 0, stream>>>(
        x, Wp0, Wp1, bih0, bhh0, bih1, bhh1, h1buf, h2buf, bar);

    fc_kernel<<<B_, 64, 0, stream>>>(h2buf + BH, Wfc, bfc, out);
}